// Round 5
// baseline (115.115 us; speedup 1.0000x reference)
//
#include <hip/hip_runtime.h>
#include <hip/hip_bf16.h>

// Problem constants (match reference)
#define BATCH 4096
#define NC    1024   // n_concepts (K)
#define NL    512    // n_lemmas   (N)
#define TSTEPS 50
#define GAMMA_C 0.95f
#define KAPPA_C 0.1f
#define FLOOR_C 1e-6f

typedef __attribute__((ext_vector_type(8))) short short8;  // 8 bf16 = 4 VGPRs
typedef __attribute__((ext_vector_type(4))) float f32x4;   // MFMA C/D frag

// ---------------- split fp32 -> bf16 hi + bf16 lo (RNE both) ----------------
__device__ inline void split_bf16(float x, unsigned short& h, unsigned short& l) {
    unsigned u = __float_as_uint(x);
    unsigned rh = u + 0x7FFFu + ((u >> 16) & 1u);
    h = (unsigned short)(rh >> 16);
    float hf = __uint_as_float((unsigned)h << 16);
    float r = x - hf;
    unsigned v = __float_as_uint(r);
    unsigned rl = v + 0x7FFFu + ((v >> 16) & 1u);
    l = (unsigned short)(rl >> 16);
}

__global__ __launch_bounds__(256)
void convert_split(const float* __restrict__ A, const float* __restrict__ W,
                   unsigned short* __restrict__ Ahi, unsigned short* __restrict__ Alo,
                   unsigned short* __restrict__ Whi, unsigned short* __restrict__ Wlo) {
    const int chunk = blockIdx.x * 256 + threadIdx.x;
    const int fidx  = chunk * 4;
    const float* src;
    unsigned short *dh, *dl;
    if (fidx < BATCH * NC) {
        src = A + fidx; dh = Ahi + fidx; dl = Alo + fidx;
    } else {
        const int o = fidx - BATCH * NC;
        src = W + o; dh = Whi + o; dl = Wlo + o;
    }
    const float4 v = *(const float4*)src;
    ushort4 h4, l4;
    split_bf16(v.x, h4.x, l4.x);
    split_bf16(v.y, h4.y, l4.y);
    split_bf16(v.z, h4.z, l4.z);
    split_bf16(v.w, h4.w, l4.w);
    *(ushort4*)dh = h4;
    *(ushort4*)dl = l4;
}

// ------------- MFMA GEMM: D = Ahi*Whi^T + Ahi*Wlo^T + Alo*Whi^T -------------
// Block tile 128(M) x 256(N), 512 thr = 8 waves as 2(M) x 4(N), wave-tile
// 64x64 = 4x4 sites of 16x16x32 bf16 MFMA. splitK=4 -> 256 blocks (1/CU).
// Balance: per stage/wave 16 ds_read_b128 vs 48 MFMA -> LDS & MFMA pipes even.
#define TM 128
#define TN 256
#define GK 32     // K per LDS stage
#define LDT 40    // ushort stride per LDS row (80 B: fragment reads 2-way max)

__global__ __launch_bounds__(512)
void gemm_bf16x2(const unsigned short* __restrict__ Ahi, const unsigned short* __restrict__ Alo,
                 const unsigned short* __restrict__ Whi, const unsigned short* __restrict__ Wlo,
                 float* __restrict__ Dp, int kPerSplit) {
    __shared__ unsigned short AsH[TM * LDT];   // 10 KB
    __shared__ unsigned short AsL[TM * LDT];   // 10 KB
    __shared__ unsigned short BsH[TN * LDT];   // 20 KB
    __shared__ unsigned short BsL[TN * LDT];   // 20 KB

    const int tid = threadIdx.x;
    const int m0 = blockIdx.x * TM;
    const int n0 = blockIdx.y * TN;
    const int kb = blockIdx.z * kPerSplit;

    // ---- staging ownership ----
    // A: 128 rows x 32 k -> thread t: row t>>2, k-chunk (t&3)*8   (1 short8 each)
    // B: 256 rows x 32 k -> thread t: row t>>1, k-chunks (t&1)*16 + {0,8}
    const int srA = tid >> 2;
    const int kcA = (tid & 3) * 8;
    const int srB = tid >> 1;
    const int kcB = (tid & 1) * 16;

    const unsigned short* gAh = Ahi + (size_t)(m0 + srA) * NC + kb + kcA;
    const unsigned short* gAl = Alo + (size_t)(m0 + srA) * NC + kb + kcA;
    const unsigned short* gBh = Whi + (size_t)(n0 + srB) * NC + kb + kcB;
    const unsigned short* gBl = Wlo + (size_t)(n0 + srB) * NC + kb + kcB;

    unsigned short* wAh = AsH + srA * LDT + kcA;
    unsigned short* wAl = AsL + srA * LDT + kcA;
    unsigned short* wBh = BsH + srB * LDT + kcB;
    unsigned short* wBl = BsL + srB * LDT + kcB;

    // ---- wave layout: 8 waves as 2(M) x 4(N), wave-tile 64x64 ----
    const int lane = tid & 63;
    const int w    = tid >> 6;
    const int mw   = (w >> 2) * 64;
    const int nw   = (w & 3) * 64;
    const int sr   = lane & 15;
    const int quad = lane >> 4;

    const unsigned short* rAh = AsH + (mw + sr) * LDT + quad * 8;
    const unsigned short* rAl = AsL + (mw + sr) * LDT + quad * 8;
    const unsigned short* rBh = BsH + (nw + sr) * LDT + quad * 8;
    const unsigned short* rBl = BsL + (nw + sr) * LDT + quad * 8;

    f32x4 acc[4][4];
    #pragma unroll
    for (int i = 0; i < 4; ++i)
        #pragma unroll
        for (int j = 0; j < 4; ++j)
            acc[i][j] = (f32x4){0.f, 0.f, 0.f, 0.f};

    // prologue: first stage into regs
    short8 pAh = *(const short8*)gAh;
    short8 pAl = *(const short8*)gAl;
    short8 pBh0 = *(const short8*)gBh;
    short8 pBh1 = *(const short8*)(gBh + 8);
    short8 pBl0 = *(const short8*)gBl;
    short8 pBl1 = *(const short8*)(gBl + 8);

    for (int kt = 0; kt < kPerSplit; kt += GK) {
        // commit staged regs to LDS (vmcnt drained here, after prior compute)
        *(short8*)wAh = pAh;
        *(short8*)wAl = pAl;
        *(short8*)wBh = pBh0;
        *(short8*)(wBh + 8) = pBh1;
        *(short8*)wBl = pBl0;
        *(short8*)(wBl + 8) = pBl1;
        __syncthreads();

        // issue next stage's global loads (whole compute phase to land)
        const int kn = (kt + GK < kPerSplit) ? kt + GK : 0;  // harmless wrap
        pAh = *(const short8*)(gAh + kn);
        pAl = *(const short8*)(gAl + kn);
        pBh0 = *(const short8*)(gBh + kn);
        pBh1 = *(const short8*)(gBh + kn + 8);
        pBl0 = *(const short8*)(gBl + kn);
        pBl1 = *(const short8*)(gBl + kn + 8);

        // fragments: 8 A + 8 B ds_read_b128
        short8 afh[4], afl[4], bfh[4], bfl[4];
        #pragma unroll
        for (int mi = 0; mi < 4; ++mi) {
            afh[mi] = *(const short8*)(rAh + mi * 16 * LDT);
            afl[mi] = *(const short8*)(rAl + mi * 16 * LDT);
        }
        #pragma unroll
        for (int ni = 0; ni < 4; ++ni) {
            bfh[ni] = *(const short8*)(rBh + ni * 16 * LDT);
            bfl[ni] = *(const short8*)(rBl + ni * 16 * LDT);
        }

        // 48 MFMAs: 16 sites x (hi*hi + hi*lo + lo*hi)
        #pragma unroll
        for (int mi = 0; mi < 4; ++mi) {
            #pragma unroll
            for (int ni = 0; ni < 4; ++ni) {
                acc[mi][ni] = __builtin_amdgcn_mfma_f32_16x16x32_bf16(
                    afh[mi], bfh[ni], acc[mi][ni], 0, 0, 0);
                acc[mi][ni] = __builtin_amdgcn_mfma_f32_16x16x32_bf16(
                    afh[mi], bfl[ni], acc[mi][ni], 0, 0, 0);
                acc[mi][ni] = __builtin_amdgcn_mfma_f32_16x16x32_bf16(
                    afl[mi], bfh[ni], acc[mi][ni], 0, 0, 0);
            }
        }
        __syncthreads();
    }

    // epilogue: C/D layout col = lane&15, row = quad*4 + reg  [m89/m91]
    float* Dz = Dp + (size_t)blockIdx.z * BATCH * NL;
    #pragma unroll
    for (int mi = 0; mi < 4; ++mi) {
        #pragma unroll
        for (int ni = 0; ni < 4; ++ni) {
            const int col = n0 + nw + ni * 16 + sr;
            #pragma unroll
            for (int r = 0; r < 4; ++r) {
                const int row = m0 + mw + mi * 16 + quad * 4 + r;
                Dz[(size_t)row * NL + col] = acc[mi][ni][r];
            }
        }
    }
}

// ------ 50-step recurrence + selection: 32 lanes per row, 16 cols/lane ------
template<int SK>
__global__ __launch_bounds__(256)
void iterate_select(const float* __restrict__ Dp,
                    float* __restrict__ a_out,
                    float* __restrict__ sel_out, float* __restrict__ conf_out) {
    const int lane = threadIdx.x & 63;
    const int wave = threadIdx.x >> 6;
    const int sub  = lane & 31;
    const int grp  = lane >> 5;
    const int row  = blockIdx.x * 8 + wave * 2 + grp;

    float d[16];
    {
        const float4* p0 = (const float4*)(Dp + (size_t)row * NL + sub * 16);
        #pragma unroll
        for (int p = 0; p < 4; ++p) {
            const float4 v = p0[p];
            d[4 * p + 0] = v.x; d[4 * p + 1] = v.y; d[4 * p + 2] = v.z; d[4 * p + 3] = v.w;
        }
        #pragma unroll
        for (int s = 1; s < SK; ++s) {
            const float4* ps = (const float4*)(Dp + (size_t)s * BATCH * NL
                                               + (size_t)row * NL + sub * 16);
            #pragma unroll
            for (int p = 0; p < 4; ++p) {
                const float4 v = ps[p];
                d[4 * p + 0] += v.x; d[4 * p + 1] += v.y;
                d[4 * p + 2] += v.z; d[4 * p + 3] += v.w;
            }
        }
    }

    float a[16];
    #pragma unroll
    for (int j = 0; j < 16; ++j) a[j] = 0.f;

    const float K1 = 1.0f + KAPPA_C;

    for (int t = 0; t < TSTEPS; ++t) {
        #pragma unroll
        for (int j = 0; j < 16; ++j) a[j] = fmaf(GAMMA_C, a[j], d[j]);

        float t8[8], t4[4], t2[2];
        #pragma unroll
        for (int j = 0; j < 8; ++j) t8[j] = a[j] + a[j + 8];
        #pragma unroll
        for (int j = 0; j < 4; ++j) t4[j] = t8[j] + t8[j + 4];
        t2[0] = t4[0] + t4[2]; t2[1] = t4[1] + t4[3];
        float S = t2[0] + t2[1];

        S += __shfl_xor(S, 1, 64);
        S += __shfl_xor(S, 2, 64);
        S += __shfl_xor(S, 4, 64);
        S += __shfl_xor(S, 8, 64);
        S += __shfl_xor(S, 16, 64);

        const float h = -KAPPA_C * S;
        #pragma unroll
        for (int j = 0; j < 16; ++j) {
            const float v = fmaf(K1, a[j], h);
            a[j] = v > 0.f ? v : 0.f;
        }
    }

    float m8[8], m4[4], s8[8], s4[4];
    #pragma unroll
    for (int j = 0; j < 8; ++j) { m8[j] = fmaxf(a[j], a[j + 8]); s8[j] = a[j] + a[j + 8]; }
    #pragma unroll
    for (int j = 0; j < 4; ++j) { m4[j] = fmaxf(m8[j], m8[j + 4]); s4[j] = s8[j] + s8[j + 4]; }
    float peak = fmaxf(fmaxf(m4[0], m4[1]), fmaxf(m4[2], m4[3]));
    float ssum = (s4[0] + s4[1]) + (s4[2] + s4[3]);

    peak = fmaxf(peak, __shfl_xor(peak, 1, 64));
    peak = fmaxf(peak, __shfl_xor(peak, 2, 64));
    peak = fmaxf(peak, __shfl_xor(peak, 4, 64));
    peak = fmaxf(peak, __shfl_xor(peak, 8, 64));
    peak = fmaxf(peak, __shfl_xor(peak, 16, 64));
    ssum += __shfl_xor(ssum, 1, 64);
    ssum += __shfl_xor(ssum, 2, 64);
    ssum += __shfl_xor(ssum, 4, 64);
    ssum += __shfl_xor(ssum, 8, 64);
    ssum += __shfl_xor(ssum, 16, 64);

    const float mean = ssum * (1.0f / (float)NL);
    const float conf = peak / fmaxf(mean, FLOOR_C);

    int idx = 0x7fffffff;
    #pragma unroll
    for (int j = 0; j < 16; ++j)
        if (a[j] == peak) idx = min(idx, sub * 16 + j);
    idx = min(idx, __shfl_xor(idx, 1, 64));
    idx = min(idx, __shfl_xor(idx, 2, 64));
    idx = min(idx, __shfl_xor(idx, 4, 64));
    idx = min(idx, __shfl_xor(idx, 8, 64));
    idx = min(idx, __shfl_xor(idx, 16, 64));

    float4* ar = (float4*)(a_out + (size_t)row * NL + sub * 16);
    #pragma unroll
    for (int p = 0; p < 4; ++p) {
        float4 v;
        v.x = a[4 * p + 0]; v.y = a[4 * p + 1]; v.z = a[4 * p + 2]; v.w = a[4 * p + 3];
        ar[p] = v;
    }

    if (sub == 0) {
        if (sel_out)  sel_out[row]  = (float)idx;
        if (conf_out) conf_out[row] = conf;
    }
}

extern "C" void kernel_launch(void* const* d_in, const int* in_sizes, int n_in,
                              void* d_out, int out_size, void* d_ws, size_t ws_size,
                              hipStream_t stream) {
    const float* c_lex = (const float*)d_in[0];
    const float* W     = (const float*)d_in[1];
    // d_in[2] = a0 (zeros at every reset; recurrence inits a=0 directly)

    // workspace layout (~52.8 MB; ws ~268 MB per fill counters):
    float* D = (float*)d_ws;                                     // 4 x 8.39 MB
    unsigned short* Ahi = (unsigned short*)(D + 4ull * BATCH * NL);
    unsigned short* Alo = Ahi + (size_t)BATCH * NC;
    unsigned short* Whi = Alo + (size_t)BATCH * NC;
    unsigned short* Wlo = Whi + (size_t)NL * NC;

    float* a_out = (float*)d_out;
    float* sel   = nullptr;
    float* conf  = nullptr;
    const int base = BATCH * NL;
    if (out_size >= base + 2 * BATCH) {        // (a, selected, confidence)
        sel  = a_out + base;
        conf = a_out + base + BATCH;
    } else if (out_size >= base + BATCH) {     // (a, confidence)
        conf = a_out + base;
    }

    // 1) split fp32 -> bf16 hi/lo
    convert_split<<<dim3(4608), 256, 0, stream>>>(c_lex, W, Ahi, Alo, Whi, Wlo);

    // 2) MFMA GEMM, splitK=4: grid (32,2,4) = 256 blocks = 1 per CU
    const int kPerSplit = NC / 4;
    gemm_bf16x2<<<dim3(BATCH / TM, NL / TN, 4), 512, 0, stream>>>(
        Ahi, Alo, Whi, Wlo, D, kPerSplit);

    // 3) recurrence + selection (sums the 4 partials during its D load)
    iterate_select<4><<<dim3(BATCH / 8), 256, 0, stream>>>(D, a_out, sel, conf);
}

// Round 6
// 113.429 us; speedup vs baseline: 1.0149x; 1.0149x over previous
//
#include <hip/hip_runtime.h>
#include <hip/hip_bf16.h>

// Problem constants (match reference)
#define BATCH 4096
#define NC    1024   // n_concepts (K)
#define NL    512    // n_lemmas   (N)
#define TSTEPS 50
#define GAMMA_C 0.95f
#define KAPPA_C 0.1f
#define FLOOR_C 1e-6f

typedef __attribute__((ext_vector_type(8))) short short8;  // 8 bf16 = 4 VGPRs
typedef __attribute__((ext_vector_type(4))) float f32x4;   // MFMA C/D frag

// ---------------- split fp32 -> bf16 hi + bf16 lo (RNE both) ----------------
__device__ inline void split_bf16(float x, unsigned short& h, unsigned short& l) {
    unsigned u = __float_as_uint(x);
    unsigned rh = u + 0x7FFFu + ((u >> 16) & 1u);
    h = (unsigned short)(rh >> 16);
    float hf = __uint_as_float((unsigned)h << 16);
    float r = x - hf;
    unsigned v = __float_as_uint(r);
    unsigned rl = v + 0x7FFFu + ((v >> 16) & 1u);
    l = (unsigned short)(rl >> 16);
}

// W-only conversion: 512x1024 floats -> hi/lo bf16
__global__ __launch_bounds__(256)
void convert_w(const float* __restrict__ W,
               unsigned short* __restrict__ Whi, unsigned short* __restrict__ Wlo) {
    const int fidx = (blockIdx.x * 256 + threadIdx.x) * 4;
    const float4 v = *(const float4*)(W + fidx);
    ushort4 h4, l4;
    split_bf16(v.x, h4.x, l4.x);
    split_bf16(v.y, h4.y, l4.y);
    split_bf16(v.z, h4.z, l4.z);
    split_bf16(v.w, h4.w, l4.w);
    *(ushort4*)(Whi + fidx) = h4;
    *(ushort4*)(Wlo + fidx) = l4;
}

// ------------- MFMA GEMM: D = Ahi*Whi^T + Ahi*Wlo^T + Alo*Whi^T -------------
// A read as fp32 and hi/lo-split in-register during staging (saves the
// convert pass over A). Block tile 128(M) x 256(N), 512 thr = 8 waves as
// 2(M) x 4(N), wave-tile 64x64 = 4x4 sites of 16x16x32 bf16 MFMA.
// splitK=4 -> grid (32,2,4) = 256 blocks = 1/CU.
#define TM 128
#define TN 256
#define GK 32     // K per LDS stage
#define LDT 40    // ushort stride per LDS row (80 B: fragment reads 2-way max)

__global__ __launch_bounds__(512)
void gemm_bf16x2(const float* __restrict__ A,
                 const unsigned short* __restrict__ Whi, const unsigned short* __restrict__ Wlo,
                 float* __restrict__ Dp, int kPerSplit) {
    __shared__ unsigned short AsH[TM * LDT];   // 10 KB
    __shared__ unsigned short AsL[TM * LDT];   // 10 KB
    __shared__ unsigned short BsH[TN * LDT];   // 20 KB
    __shared__ unsigned short BsL[TN * LDT];   // 20 KB

    const int tid = threadIdx.x;
    const int m0 = blockIdx.x * TM;
    const int n0 = blockIdx.y * TN;
    const int kb = blockIdx.z * kPerSplit;

    // ---- staging ownership ----
    // A (fp32): 128 rows x 32 k -> thread t: row t>>2, k-offset (t&3)*8, 8 floats
    // B (bf16 hi/lo): 256 rows x 32 k -> thread t: row t>>1, k-offset (t&1)*16
    const int srA = tid >> 2;
    const int kcA = (tid & 3) * 8;
    const int srB = tid >> 1;
    const int kcB = (tid & 1) * 16;

    const float*          gA  = A   + (size_t)(m0 + srA) * NC + kb + kcA;
    const unsigned short* gBh = Whi + (size_t)(n0 + srB) * NC + kb + kcB;
    const unsigned short* gBl = Wlo + (size_t)(n0 + srB) * NC + kb + kcB;

    unsigned short* wAh = AsH + srA * LDT + kcA;
    unsigned short* wAl = AsL + srA * LDT + kcA;
    unsigned short* wBh = BsH + srB * LDT + kcB;
    unsigned short* wBl = BsL + srB * LDT + kcB;

    // ---- wave layout: 8 waves as 2(M) x 4(N), wave-tile 64x64 ----
    const int lane = tid & 63;
    const int w    = tid >> 6;
    const int mw   = (w >> 2) * 64;
    const int nw   = (w & 3) * 64;
    const int sr   = lane & 15;
    const int quad = lane >> 4;

    const unsigned short* rAh = AsH + (mw + sr) * LDT + quad * 8;
    const unsigned short* rAl = AsL + (mw + sr) * LDT + quad * 8;
    const unsigned short* rBh = BsH + (nw + sr) * LDT + quad * 8;
    const unsigned short* rBl = BsL + (nw + sr) * LDT + quad * 8;

    f32x4 acc[4][4];
    #pragma unroll
    for (int i = 0; i < 4; ++i)
        #pragma unroll
        for (int j = 0; j < 4; ++j)
            acc[i][j] = (f32x4){0.f, 0.f, 0.f, 0.f};

    // prologue: first stage into regs
    float4 pA0 = *(const float4*)gA;
    float4 pA1 = *(const float4*)(gA + 4);
    short8 pBh0 = *(const short8*)gBh;
    short8 pBh1 = *(const short8*)(gBh + 8);
    short8 pBl0 = *(const short8*)gBl;
    short8 pBl1 = *(const short8*)(gBl + 8);

    for (int kt = 0; kt < kPerSplit; kt += GK) {
        // split staged fp32 A to hi/lo and commit everything to LDS
        {
            short8 h8, l8;
            const float av[8] = {pA0.x, pA0.y, pA0.z, pA0.w, pA1.x, pA1.y, pA1.z, pA1.w};
            #pragma unroll
            for (int i = 0; i < 8; ++i) {
                unsigned short h, l;
                split_bf16(av[i], h, l);
                h8[i] = (short)h; l8[i] = (short)l;
            }
            *(short8*)wAh = h8;
            *(short8*)wAl = l8;
        }
        *(short8*)wBh = pBh0;
        *(short8*)(wBh + 8) = pBh1;
        *(short8*)wBl = pBl0;
        *(short8*)(wBl + 8) = pBl1;
        __syncthreads();

        // issue next stage's global loads (whole compute phase to land)
        const int kn = (kt + GK < kPerSplit) ? kt + GK : 0;  // harmless wrap
        pA0 = *(const float4*)(gA + kn);
        pA1 = *(const float4*)(gA + kn + 4);
        pBh0 = *(const short8*)(gBh + kn);
        pBh1 = *(const short8*)(gBh + kn + 8);
        pBl0 = *(const short8*)(gBl + kn);
        pBl1 = *(const short8*)(gBl + kn + 8);

        // fragments: 8 A + 8 B ds_read_b128
        short8 afh[4], afl[4], bfh[4], bfl[4];
        #pragma unroll
        for (int mi = 0; mi < 4; ++mi) {
            afh[mi] = *(const short8*)(rAh + mi * 16 * LDT);
            afl[mi] = *(const short8*)(rAl + mi * 16 * LDT);
        }
        #pragma unroll
        for (int ni = 0; ni < 4; ++ni) {
            bfh[ni] = *(const short8*)(rBh + ni * 16 * LDT);
            bfl[ni] = *(const short8*)(rBl + ni * 16 * LDT);
        }

        // 48 MFMAs: 16 sites x (hi*hi + hi*lo + lo*hi)
        #pragma unroll
        for (int mi = 0; mi < 4; ++mi) {
            #pragma unroll
            for (int ni = 0; ni < 4; ++ni) {
                acc[mi][ni] = __builtin_amdgcn_mfma_f32_16x16x32_bf16(
                    afh[mi], bfh[ni], acc[mi][ni], 0, 0, 0);
                acc[mi][ni] = __builtin_amdgcn_mfma_f32_16x16x32_bf16(
                    afh[mi], bfl[ni], acc[mi][ni], 0, 0, 0);
                acc[mi][ni] = __builtin_amdgcn_mfma_f32_16x16x32_bf16(
                    afl[mi], bfh[ni], acc[mi][ni], 0, 0, 0);
            }
        }
        __syncthreads();
    }

    // epilogue: C/D layout col = lane&15, row = quad*4 + reg  [m89/m91]
    float* Dz = Dp + (size_t)blockIdx.z * BATCH * NL;
    #pragma unroll
    for (int mi = 0; mi < 4; ++mi) {
        #pragma unroll
        for (int ni = 0; ni < 4; ++ni) {
            const int col = n0 + nw + ni * 16 + sr;
            #pragma unroll
            for (int r = 0; r < 4; ++r) {
                const int row = m0 + mw + mi * 16 + quad * 4 + r;
                Dz[(size_t)row * NL + col] = acc[mi][ni][r];
            }
        }
    }
}

// ------ 50-step recurrence + selection: 64 lanes per row, 8 cols/lane -------
// 1 row/wave -> 4096 waves = 4 waves/SIMD: doubles the interleave factor for
// the serial per-step chain (tree sum + 6 dependent shuffle hops).
template<int SK>
__global__ __launch_bounds__(256)
void iterate_select(const float* __restrict__ Dp,
                    float* __restrict__ a_out,
                    float* __restrict__ sel_out, float* __restrict__ conf_out) {
    const int lane = threadIdx.x & 63;
    const int wave = threadIdx.x >> 6;
    const int row  = blockIdx.x * 4 + wave;

    // lane owns cols [lane*8, lane*8+8)
    float d[8];
    {
        const float4* p0 = (const float4*)(Dp + (size_t)row * NL + lane * 8);
        float4 v0 = p0[0], v1 = p0[1];
        d[0] = v0.x; d[1] = v0.y; d[2] = v0.z; d[3] = v0.w;
        d[4] = v1.x; d[5] = v1.y; d[6] = v1.z; d[7] = v1.w;
        #pragma unroll
        for (int s = 1; s < SK; ++s) {
            const float4* ps = (const float4*)(Dp + (size_t)s * BATCH * NL
                                               + (size_t)row * NL + lane * 8);
            const float4 w0 = ps[0], w1 = ps[1];
            d[0] += w0.x; d[1] += w0.y; d[2] += w0.z; d[3] += w0.w;
            d[4] += w1.x; d[5] += w1.y; d[6] += w1.z; d[7] += w1.w;
        }
    }

    float a[8];
    #pragma unroll
    for (int j = 0; j < 8; ++j) a[j] = 0.f;

    const float K1 = 1.0f + KAPPA_C;

    for (int t = 0; t < TSTEPS; ++t) {
        #pragma unroll
        for (int j = 0; j < 8; ++j) a[j] = fmaf(GAMMA_C, a[j], d[j]);

        // tree sum of 8 locals (depth 3)
        float t4a = a[0] + a[4], t4b = a[1] + a[5], t4c = a[2] + a[6], t4d = a[3] + a[7];
        float t2a = t4a + t4c, t2b = t4b + t4d;
        float S = t2a + t2b;

        // full-wave butterfly (6 hops)
        S += __shfl_xor(S, 1, 64);
        S += __shfl_xor(S, 2, 64);
        S += __shfl_xor(S, 4, 64);
        S += __shfl_xor(S, 8, 64);
        S += __shfl_xor(S, 16, 64);
        S += __shfl_xor(S, 32, 64);

        const float h = -KAPPA_C * S;
        #pragma unroll
        for (int j = 0; j < 8; ++j) {
            const float v = fmaf(K1, a[j], h);
            a[j] = v > 0.f ? v : 0.f;
        }
    }

    // ---- epilogue: peak, sum, confidence, first-index argmax ----
    float m4a = fmaxf(a[0], a[4]), m4b = fmaxf(a[1], a[5]);
    float m4c = fmaxf(a[2], a[6]), m4d = fmaxf(a[3], a[7]);
    float peak = fmaxf(fmaxf(m4a, m4b), fmaxf(m4c, m4d));
    float s4a = a[0] + a[4], s4b = a[1] + a[5], s4c = a[2] + a[6], s4d = a[3] + a[7];
    float ssum = (s4a + s4b) + (s4c + s4d);

    #pragma unroll
    for (int m = 1; m < 64; m <<= 1) {
        peak = fmaxf(peak, __shfl_xor(peak, m, 64));
        ssum += __shfl_xor(ssum, m, 64);
    }

    const float mean = ssum * (1.0f / (float)NL);
    const float conf = peak / fmaxf(mean, FLOOR_C);

    int idx = 0x7fffffff;
    #pragma unroll
    for (int j = 0; j < 8; ++j)
        if (a[j] == peak) idx = min(idx, lane * 8 + j);
    #pragma unroll
    for (int m = 1; m < 64; m <<= 1)
        idx = min(idx, __shfl_xor(idx, m, 64));

    float4* ar = (float4*)(a_out + (size_t)row * NL + lane * 8);
    float4 o0, o1;
    o0.x = a[0]; o0.y = a[1]; o0.z = a[2]; o0.w = a[3];
    o1.x = a[4]; o1.y = a[5]; o1.z = a[6]; o1.w = a[7];
    ar[0] = o0; ar[1] = o1;

    if (lane == 0) {
        if (sel_out)  sel_out[row]  = (float)idx;
        if (conf_out) conf_out[row] = conf;
    }
}

extern "C" void kernel_launch(void* const* d_in, const int* in_sizes, int n_in,
                              void* d_out, int out_size, void* d_ws, size_t ws_size,
                              hipStream_t stream) {
    const float* c_lex = (const float*)d_in[0];
    const float* W     = (const float*)d_in[1];
    // d_in[2] = a0 (zeros at every reset; recurrence inits a=0 directly)

    // workspace layout: 4 D-partials (33.6 MB) + Whi/Wlo (2.1 MB)
    float* D = (float*)d_ws;
    unsigned short* Whi = (unsigned short*)(D + 4ull * BATCH * NL);
    unsigned short* Wlo = Whi + (size_t)NL * NC;

    float* a_out = (float*)d_out;
    float* sel   = nullptr;
    float* conf  = nullptr;
    const int base = BATCH * NL;
    if (out_size >= base + 2 * BATCH) {        // (a, selected, confidence)
        sel  = a_out + base;
        conf = a_out + base + BATCH;
    } else if (out_size >= base + BATCH) {     // (a, confidence)
        conf = a_out + base;
    }

    // 1) W fp32 -> bf16 hi/lo  (524288 floats / 4 per thread)
    convert_w<<<dim3(512), 256, 0, stream>>>(W, Whi, Wlo);

    // 2) MFMA GEMM (A split in-kernel), splitK=4: grid (32,2,4) = 256 blocks
    const int kPerSplit = NC / 4;
    gemm_bf16x2<<<dim3(BATCH / TM, NL / TN, 4), 512, 0, stream>>>(
        c_lex, Whi, Wlo, D, kPerSplit);

    // 3) recurrence + selection: 1 row/wave, 4 waves/SIMD
    iterate_select<4><<<dim3(BATCH / 4), 256, 0, stream>>>(D, a_out, sel, conf);
}

// Round 7
// 113.165 us; speedup vs baseline: 1.0172x; 1.0023x over previous
//
#include <hip/hip_runtime.h>
#include <hip/hip_bf16.h>

// Problem constants (match reference)
#define BATCH 4096
#define NC    1024   // n_concepts (K)
#define NL    512    // n_lemmas   (N)
#define TSTEPS 50
#define GAMMA_C 0.95f
#define KAPPA_C 0.1f
#define FLOOR_C 1e-6f

typedef __attribute__((ext_vector_type(8))) short short8;  // 8 bf16 = 4 VGPRs
typedef __attribute__((ext_vector_type(4))) float f32x4;   // MFMA C/D frag

// ---------------- split fp32 -> bf16 hi + bf16 lo (RNE both) ----------------
__device__ inline void split_bf16(float x, unsigned short& h, unsigned short& l) {
    unsigned u = __float_as_uint(x);
    unsigned rh = u + 0x7FFFu + ((u >> 16) & 1u);
    h = (unsigned short)(rh >> 16);
    float hf = __uint_as_float((unsigned)h << 16);
    float r = x - hf;
    unsigned v = __float_as_uint(r);
    unsigned rl = v + 0x7FFFu + ((v >> 16) & 1u);
    l = (unsigned short)(rl >> 16);
}

// W-only conversion: 512x1024 floats -> hi/lo bf16
__global__ __launch_bounds__(256)
void convert_w(const float* __restrict__ W,
               unsigned short* __restrict__ Whi, unsigned short* __restrict__ Wlo) {
    const int fidx = (blockIdx.x * 256 + threadIdx.x) * 4;
    const float4 v = *(const float4*)(W + fidx);
    ushort4 h4, l4;
    split_bf16(v.x, h4.x, l4.x);
    split_bf16(v.y, h4.y, l4.y);
    split_bf16(v.z, h4.z, l4.z);
    split_bf16(v.w, h4.w, l4.w);
    *(ushort4*)(Whi + fidx) = h4;
    *(ushort4*)(Wlo + fidx) = l4;
}

// ------------- MFMA GEMM: D = Ahi*Whi^T + Ahi*Wlo^T + Alo*Whi^T -------------
// Block tile 128 x 128, 256 thr = 4 waves as 2(M) x 2(N), wave-tile 64x64.
// LDS 40 KB -> 2 blocks/CU: barrier drains of one block overlap the other
// block's compute (m114 co-scheduling) — the r6 1-block/CU structure exposed
// every __syncthreads vmcnt(0) drain. splitK=4 -> grid (32,4,4)=512 blocks.
#define TM 128
#define TN 128
#define GK 32     // K per LDS stage
#define LDT 40    // ushort stride per LDS row (80 B: fragment reads 2-way max)

__global__ __launch_bounds__(256)
void gemm_bf16x2(const float* __restrict__ A,
                 const unsigned short* __restrict__ Whi, const unsigned short* __restrict__ Wlo,
                 float* __restrict__ Dp, int kPerSplit) {
    __shared__ unsigned short AsH[TM * LDT];   // 10 KB
    __shared__ unsigned short AsL[TM * LDT];   // 10 KB
    __shared__ unsigned short BsH[TN * LDT];   // 10 KB
    __shared__ unsigned short BsL[TN * LDT];   // 10 KB

    const int tid = threadIdx.x;
    const int m0 = blockIdx.x * TM;
    const int n0 = blockIdx.y * TN;
    const int kb = blockIdx.z * kPerSplit;

    // ---- staging ownership (256 thr) ----
    // A (fp32): 128 rows x 32 k -> thread t: row t>>1, k-off (t&1)*16, 16 floats
    // B (bf16 hi/lo): 128 rows x 32 k -> same row/k-off, 16 shorts per buffer
    const int sr0 = tid >> 1;
    const int kc0 = (tid & 1) * 16;

    const float*          gA  = A   + (size_t)(m0 + sr0) * NC + kb + kc0;
    const unsigned short* gBh = Whi + (size_t)(n0 + sr0) * NC + kb + kc0;
    const unsigned short* gBl = Wlo + (size_t)(n0 + sr0) * NC + kb + kc0;

    unsigned short* wAh = AsH + sr0 * LDT + kc0;
    unsigned short* wAl = AsL + sr0 * LDT + kc0;
    unsigned short* wBh = BsH + sr0 * LDT + kc0;
    unsigned short* wBl = BsL + sr0 * LDT + kc0;

    // ---- wave layout: 4 waves as 2(M) x 2(N), wave-tile 64x64 ----
    const int lane = tid & 63;
    const int w    = tid >> 6;
    const int mw   = (w >> 1) * 64;
    const int nw   = (w & 1) * 64;
    const int sr   = lane & 15;
    const int quad = lane >> 4;

    const unsigned short* rAh = AsH + (mw + sr) * LDT + quad * 8;
    const unsigned short* rAl = AsL + (mw + sr) * LDT + quad * 8;
    const unsigned short* rBh = BsH + (nw + sr) * LDT + quad * 8;
    const unsigned short* rBl = BsL + (nw + sr) * LDT + quad * 8;

    f32x4 acc[4][4];
    #pragma unroll
    for (int i = 0; i < 4; ++i)
        #pragma unroll
        for (int j = 0; j < 4; ++j)
            acc[i][j] = (f32x4){0.f, 0.f, 0.f, 0.f};

    // prologue: first stage into regs (A: 4x float4; B: 2+2 short8)
    float4 pA0 = *(const float4*)gA;
    float4 pA1 = *(const float4*)(gA + 4);
    float4 pA2 = *(const float4*)(gA + 8);
    float4 pA3 = *(const float4*)(gA + 12);
    short8 pBh0 = *(const short8*)gBh;
    short8 pBh1 = *(const short8*)(gBh + 8);
    short8 pBl0 = *(const short8*)gBl;
    short8 pBl1 = *(const short8*)(gBl + 8);

    for (int kt = 0; kt < kPerSplit; kt += GK) {
        // split staged fp32 A to hi/lo and commit everything to LDS
        {
            short8 h8a, l8a, h8b, l8b;
            const float av[16] = {pA0.x, pA0.y, pA0.z, pA0.w,
                                  pA1.x, pA1.y, pA1.z, pA1.w,
                                  pA2.x, pA2.y, pA2.z, pA2.w,
                                  pA3.x, pA3.y, pA3.z, pA3.w};
            #pragma unroll
            for (int i = 0; i < 8; ++i) {
                unsigned short h, l;
                split_bf16(av[i], h, l);
                h8a[i] = (short)h; l8a[i] = (short)l;
            }
            #pragma unroll
            for (int i = 0; i < 8; ++i) {
                unsigned short h, l;
                split_bf16(av[8 + i], h, l);
                h8b[i] = (short)h; l8b[i] = (short)l;
            }
            *(short8*)wAh = h8a;
            *(short8*)(wAh + 8) = h8b;
            *(short8*)wAl = l8a;
            *(short8*)(wAl + 8) = l8b;
        }
        *(short8*)wBh = pBh0;
        *(short8*)(wBh + 8) = pBh1;
        *(short8*)wBl = pBl0;
        *(short8*)(wBl + 8) = pBl1;
        __syncthreads();

        // issue next stage's global loads
        const int kn = (kt + GK < kPerSplit) ? kt + GK : 0;  // harmless wrap
        pA0 = *(const float4*)(gA + kn);
        pA1 = *(const float4*)(gA + kn + 4);
        pA2 = *(const float4*)(gA + kn + 8);
        pA3 = *(const float4*)(gA + kn + 12);
        pBh0 = *(const short8*)(gBh + kn);
        pBh1 = *(const short8*)(gBh + kn + 8);
        pBl0 = *(const short8*)(gBl + kn);
        pBl1 = *(const short8*)(gBl + kn + 8);

        // fragments: 8 A + 8 B ds_read_b128
        short8 afh[4], afl[4], bfh[4], bfl[4];
        #pragma unroll
        for (int mi = 0; mi < 4; ++mi) {
            afh[mi] = *(const short8*)(rAh + mi * 16 * LDT);
            afl[mi] = *(const short8*)(rAl + mi * 16 * LDT);
        }
        #pragma unroll
        for (int ni = 0; ni < 4; ++ni) {
            bfh[ni] = *(const short8*)(rBh + ni * 16 * LDT);
            bfl[ni] = *(const short8*)(rBl + ni * 16 * LDT);
        }

        // 48 MFMAs: 16 sites x (hi*hi + hi*lo + lo*hi)
        #pragma unroll
        for (int mi = 0; mi < 4; ++mi) {
            #pragma unroll
            for (int ni = 0; ni < 4; ++ni) {
                acc[mi][ni] = __builtin_amdgcn_mfma_f32_16x16x32_bf16(
                    afh[mi], bfh[ni], acc[mi][ni], 0, 0, 0);
                acc[mi][ni] = __builtin_amdgcn_mfma_f32_16x16x32_bf16(
                    afh[mi], bfl[ni], acc[mi][ni], 0, 0, 0);
                acc[mi][ni] = __builtin_amdgcn_mfma_f32_16x16x32_bf16(
                    afl[mi], bfh[ni], acc[mi][ni], 0, 0, 0);
            }
        }
        __syncthreads();
    }

    // epilogue: C/D layout col = lane&15, row = quad*4 + reg  [m89/m91]
    float* Dz = Dp + (size_t)blockIdx.z * BATCH * NL;
    #pragma unroll
    for (int mi = 0; mi < 4; ++mi) {
        #pragma unroll
        for (int ni = 0; ni < 4; ++ni) {
            const int col = n0 + nw + ni * 16 + sr;
            #pragma unroll
            for (int r = 0; r < 4; ++r) {
                const int row = m0 + mw + mi * 16 + quad * 4 + r;
                Dz[(size_t)row * NL + col] = acc[mi][ni][r];
            }
        }
    }
}

// ------ 50-step recurrence + selection: 64 lanes per row, 8 cols/lane -------
template<int SK>
__global__ __launch_bounds__(256)
void iterate_select(const float* __restrict__ Dp,
                    float* __restrict__ a_out,
                    float* __restrict__ sel_out, float* __restrict__ conf_out) {
    const int lane = threadIdx.x & 63;
    const int wave = threadIdx.x >> 6;
    const int row  = blockIdx.x * 4 + wave;

    float d[8];
    {
        const float4* p0 = (const float4*)(Dp + (size_t)row * NL + lane * 8);
        float4 v0 = p0[0], v1 = p0[1];
        d[0] = v0.x; d[1] = v0.y; d[2] = v0.z; d[3] = v0.w;
        d[4] = v1.x; d[5] = v1.y; d[6] = v1.z; d[7] = v1.w;
        #pragma unroll
        for (int s = 1; s < SK; ++s) {
            const float4* ps = (const float4*)(Dp + (size_t)s * BATCH * NL
                                               + (size_t)row * NL + lane * 8);
            const float4 w0 = ps[0], w1 = ps[1];
            d[0] += w0.x; d[1] += w0.y; d[2] += w0.z; d[3] += w0.w;
            d[4] += w1.x; d[5] += w1.y; d[6] += w1.z; d[7] += w1.w;
        }
    }

    float a[8];
    #pragma unroll
    for (int j = 0; j < 8; ++j) a[j] = 0.f;

    const float K1 = 1.0f + KAPPA_C;

    for (int t = 0; t < TSTEPS; ++t) {
        #pragma unroll
        for (int j = 0; j < 8; ++j) a[j] = fmaf(GAMMA_C, a[j], d[j]);

        float t4a = a[0] + a[4], t4b = a[1] + a[5], t4c = a[2] + a[6], t4d = a[3] + a[7];
        float t2a = t4a + t4c, t2b = t4b + t4d;
        float S = t2a + t2b;

        S += __shfl_xor(S, 1, 64);
        S += __shfl_xor(S, 2, 64);
        S += __shfl_xor(S, 4, 64);
        S += __shfl_xor(S, 8, 64);
        S += __shfl_xor(S, 16, 64);
        S += __shfl_xor(S, 32, 64);

        const float h = -KAPPA_C * S;
        #pragma unroll
        for (int j = 0; j < 8; ++j) {
            const float v = fmaf(K1, a[j], h);
            a[j] = v > 0.f ? v : 0.f;
        }
    }

    float m4a = fmaxf(a[0], a[4]), m4b = fmaxf(a[1], a[5]);
    float m4c = fmaxf(a[2], a[6]), m4d = fmaxf(a[3], a[7]);
    float peak = fmaxf(fmaxf(m4a, m4b), fmaxf(m4c, m4d));
    float s4a = a[0] + a[4], s4b = a[1] + a[5], s4c = a[2] + a[6], s4d = a[3] + a[7];
    float ssum = (s4a + s4b) + (s4c + s4d);

    #pragma unroll
    for (int m = 1; m < 64; m <<= 1) {
        peak = fmaxf(peak, __shfl_xor(peak, m, 64));
        ssum += __shfl_xor(ssum, m, 64);
    }

    const float mean = ssum * (1.0f / (float)NL);
    const float conf = peak / fmaxf(mean, FLOOR_C);

    int idx = 0x7fffffff;
    #pragma unroll
    for (int j = 0; j < 8; ++j)
        if (a[j] == peak) idx = min(idx, lane * 8 + j);
    #pragma unroll
    for (int m = 1; m < 64; m <<= 1)
        idx = min(idx, __shfl_xor(idx, m, 64));

    float4* ar = (float4*)(a_out + (size_t)row * NL + lane * 8);
    float4 o0, o1;
    o0.x = a[0]; o0.y = a[1]; o0.z = a[2]; o0.w = a[3];
    o1.x = a[4]; o1.y = a[5]; o1.z = a[6]; o1.w = a[7];
    ar[0] = o0; ar[1] = o1;

    if (lane == 0) {
        if (sel_out)  sel_out[row]  = (float)idx;
        if (conf_out) conf_out[row] = conf;
    }
}

extern "C" void kernel_launch(void* const* d_in, const int* in_sizes, int n_in,
                              void* d_out, int out_size, void* d_ws, size_t ws_size,
                              hipStream_t stream) {
    const float* c_lex = (const float*)d_in[0];
    const float* W     = (const float*)d_in[1];
    // d_in[2] = a0 (zeros at every reset; recurrence inits a=0 directly)

    // workspace layout: 4 D-partials (33.6 MB) + Whi/Wlo (2.1 MB)
    float* D = (float*)d_ws;
    unsigned short* Whi = (unsigned short*)(D + 4ull * BATCH * NL);
    unsigned short* Wlo = Whi + (size_t)NL * NC;

    float* a_out = (float*)d_out;
    float* sel   = nullptr;
    float* conf  = nullptr;
    const int base = BATCH * NL;
    if (out_size >= base + 2 * BATCH) {        // (a, selected, confidence)
        sel  = a_out + base;
        conf = a_out + base + BATCH;
    } else if (out_size >= base + BATCH) {     // (a, confidence)
        conf = a_out + base;
    }

    // 1) W fp32 -> bf16 hi/lo
    convert_w<<<dim3(512), 256, 0, stream>>>(W, Whi, Wlo);

    // 2) MFMA GEMM, 128x128 blocks, 2 blocks/CU: grid (32,4,4) = 512 blocks
    const int kPerSplit = NC / 4;
    gemm_bf16x2<<<dim3(BATCH / TM, NL / TN, 4), 256, 0, stream>>>(
        c_lex, Whi, Wlo, D, kPerSplit);

    // 3) recurrence + selection: 1 row/wave, 4 waves/SIMD
    iterate_select<4><<<dim3(BATCH / 4), 256, 0, stream>>>(D, a_out, sel, conf);
}